// Round 6
// baseline (129.008 us; speedup 1.0000x reference)
//
#include <hip/hip_runtime.h>

typedef float f32x4 __attribute__((ext_vector_type(4)));
typedef short bf16x8 __attribute__((ext_vector_type(8)));
typedef short bf16x4 __attribute__((ext_vector_type(4)));
typedef unsigned int u32x2 __attribute__((ext_vector_type(2)));

#define BS    8
#define SEQ   2048
#define DH    128
#define BQ    16
#define BK    32
#define NT    256
#define CFIX  8.0f
#define SC2E  0.12751743f       /* (1/sqrt(128)) * log2(e) */
#define NC2E  -11.541560327f    /* -CFIX * log2(e)         */

__device__ __forceinline__ unsigned short f2bf(float x) {
    unsigned u = __float_as_uint(x);
    u += 0x7FFFu + ((u >> 16) & 1u);   // RNE
    return (unsigned short)(u >> 16);
}

// async 16B global->LDS (lds dest = wave-uniform base + lane*16)
__device__ __forceinline__ void gl_lds16(const unsigned short* g, unsigned short* l) {
    __builtin_amdgcn_global_load_lds(
        (const __attribute__((address_space(1))) unsigned int*)g,
        (__attribute__((address_space(3))) unsigned int*)l, 16, 0, 0);
}

// ============================================================================
// Kernel 1: Q,K -> bf16 flat; V -> Vt[b][d][s] bf16. 256 blocks x 256 thr.
// ============================================================================
__global__ __launch_bounds__(NT)
void conv_all(const float* __restrict__ Q, const float* __restrict__ K,
              const float* __restrict__ V,
              unsigned short* __restrict__ Qbf, unsigned short* __restrict__ Kbf,
              unsigned short* __restrict__ Vt) {
    __shared__ unsigned short T[64][132];
    const int tid = threadIdx.x;
    const int bid = blockIdx.x;

    // Q,K fp32 -> bf16: 524288 float4 groups over 65536 threads (8 each)
    const int gtid = bid * NT + tid;
    #pragma unroll
    for (int i = 0; i < 8; ++i) {
        const int idx = i * (256 * NT) + gtid;
        float4 k4 = ((const float4*)K)[idx];
        float4 q4 = ((const float4*)Q)[idx];
        ushort4 hk, hq;
        hk.x = f2bf(k4.x); hk.y = f2bf(k4.y); hk.z = f2bf(k4.z); hk.w = f2bf(k4.w);
        hq.x = f2bf(q4.x); hq.y = f2bf(q4.y); hq.z = f2bf(q4.z); hq.w = f2bf(q4.w);
        ((ushort4*)Kbf)[idx] = hk;
        ((ushort4*)Qbf)[idx] = hq;
    }

    // V transpose: one 64s x 128d tile per block
    const int vb = bid >> 5, s0 = (bid & 31) * 64;
    const float* Vb = V + ((size_t)vb * SEQ + s0) * DH;
    #pragma unroll
    for (int i = 0; i < 8; ++i) {
        const int row = i * 8 + (tid >> 5);
        const int col = (tid & 31) * 4;
        float4 v = *(const float4*)(Vb + (size_t)row * DH + col);
        ushort4 h;
        h.x = f2bf(v.x); h.y = f2bf(v.y); h.z = f2bf(v.z); h.w = f2bf(v.w);
        *(ushort4*)&T[row][col] = h;
    }
    __syncthreads();
    const int d = tid >> 1, sh = (tid & 1) * 32;
    unsigned short tmp[32] __attribute__((aligned(16)));
    #pragma unroll
    for (int s = 0; s < 32; ++s) tmp[s] = T[sh + s][d];
    unsigned short* dst = Vt + ((size_t)vb * DH + d) * SEQ + s0 + sh;
    #pragma unroll
    for (int g = 0; g < 4; ++g)
        *(uint4*)(dst + g * 8) = *(const uint4*)(tmp + g * 8);
}

// ============================================================================
// Kernel 2: flash attention, BQ=16, BK=32, 4 waves, grid=1024 -> 4 blocks/CU
// (LDS 32.1 KB/block). Wave (dh=wid>>1, sh=wid&1): QK^T+softmax for the sh
// 16-key half (duplicated across dh), PV over the dh 64-d half. Small block
// + 4 independent blocks/CU: per-tile barrier drains of one block overlap
// with compute of the other three (the occupancy fix for the ~12% plateau).
// Swapped QK^T, in-register softmax, cvt_pk pack, K=16 PV all carried over.
// ============================================================================
__global__ __launch_bounds__(NT, 4)
void attn16(const unsigned short* __restrict__ Qbf, const unsigned short* __restrict__ Kbf,
            const unsigned short* __restrict__ Vt, const int* __restrict__ vlens,
            float* __restrict__ Out) {
    __shared__ unsigned short Ks[2][BK * DH];     // 2 x 8 KB (also epilogue scratch)
    __shared__ unsigned short Vs[2][DH * BK];     // 2 x 8 KB
    __shared__ float Lsc[2][16];                  // per-half row sums

    const int tid  = threadIdx.x;
    const int wid  = tid >> 6, lane = tid & 63;
    const int quad = lane >> 4, l16 = lane & 15;
    const int dh   = wid >> 1, sh = wid & 1;
    const int bid  = blockIdx.x;
    const int b    = bid >> 7;
    const int q0   = (bid & 127) * BQ;
    const int vl   = vlens[b];

    const unsigned short* Kb  = Kbf + (size_t)b * SEQ * DH;
    const unsigned short* Vtb = Vt  + (size_t)b * DH * SEQ;

    // Q fragments (rows q0+l16, bf16 pre-converted). B-frag layout == A-frag.
    bf16x8 qf[4];
    {
        const unsigned short* Qr = Qbf + ((size_t)b * SEQ + q0 + l16) * DH;
        #pragma unroll
        for (int ks = 0; ks < 4; ++ks)
            qf[ks] = *(const bf16x8*)(Qr + 32 * ks + 8 * quad);
    }

    f32x4 o[4];
    #pragma unroll
    for (int n = 0; n < 4; ++n) o[n] = (f32x4){0.f, 0.f, 0.f, 0.f};
    float lsum = 0.f;

    const int ntiles = (vl + BK - 1) >> 5;

    // staging: K tile 32r x 128d (8 KB), V tile 128d x 32k (8 KB), XOR-swizzled
    auto stage = [&](int buf, int k0) {
        unsigned short* KsB = &Ks[buf][0];
        unsigned short* VsB = &Vs[buf][0];
        #pragma unroll
        for (int ii = 0; ii < 2; ++ii) {
            const int rb = 8 * wid + 4 * ii;         // 4 K-rows per inst
            const int r  = rb + (lane >> 4);
            const int c  = lane & 15;                // 16B chunk in 256B row
            gl_lds16(Kb + (size_t)(k0 + r) * DH + ((c ^ (r & 15)) << 3),
                     KsB + (size_t)rb * DH);
        }
        #pragma unroll
        for (int jj = 0; jj < 2; ++jj) {
            const int db = 32 * wid + 16 * jj;       // 16 V d-rows per inst
            const int d  = db + (lane >> 2);
            const int c  = lane & 3;                 // 16B chunk in 64B row
            gl_lds16(Vtb + (size_t)d * SEQ + k0 + ((c ^ (d & 3)) << 3),
                     VsB + (size_t)db * BK);
        }
    };

    stage(0, 0);

    for (int t = 0; t < ntiles; ++t) {
        const int k0 = t << 5;
        __syncthreads();      // vmcnt drained: buf[t&1] staged; prev reads done
        if (t + 1 < ntiles) stage((t + 1) & 1, k0 + BK);

        const unsigned short* Kt  = &Ks[t & 1][0];
        const unsigned short* Vtl = &Vs[t & 1][0];

        // ---- S^T = K Q^T (swapped), this wave's 16-key half (dup over dh) ----
        // lane -> q=l16, keys 16sh + 4quad + r
        f32x4 s2 = (f32x4){0.f, 0.f, 0.f, 0.f};
        __builtin_amdgcn_s_setprio(1);
        #pragma unroll
        for (int ks = 0; ks < 4; ++ks) {
            const bf16x8 bk = *(const bf16x8*)(Kt + (size_t)(16 * sh + l16) * DH +
                                               (((4 * ks + quad) ^ l16) << 3));
            s2 = __builtin_amdgcn_mfma_f32_16x16x32_bf16(bk, qf[ks], s2, 0, 0, 0);
        }
        __builtin_amdgcn_s_setprio(0);

        // ---- fixed-C softmax, fully in-register ----
        float p[4];
        if (k0 + BK <= vl) {
            #pragma unroll
            for (int r = 0; r < 4; ++r) {
                const float pv = __builtin_amdgcn_exp2f(fmaf(s2[r], SC2E, NC2E));
                p[r] = pv;
                lsum += pv;
            }
        } else {
            const int kb = k0 + 16 * sh + 4 * quad;
            #pragma unroll
            for (int r = 0; r < 4; ++r) {
                float pv = __builtin_amdgcn_exp2f(fmaf(s2[r], SC2E, NC2E));
                pv = (kb + r < vl) ? pv : 0.0f;
                p[r] = pv;
                lsum += pv;
            }
        }

        // ---- pack P -> bf16 K=16 A-fragment (keys 4quad+0..3 per lane) ----
        bf16x4 pa;
        {
            unsigned w0, w1;
            asm("v_cvt_pk_bf16_f32 %0, %1, %2" : "=v"(w0) : "v"(p[0]), "v"(p[1]));
            asm("v_cvt_pk_bf16_f32 %0, %1, %2" : "=v"(w1) : "v"(p[2]), "v"(p[3]));
            u32x2 tw; tw.x = w0; tw.y = w1;
            pa = __builtin_bit_cast(bf16x4, tw);
        }

        // ---- partial O += P_half V_half over this wave's 64-d half ----
        // V frag: row d = 64dh+16n+l16 (64B), keys 16sh+4quad+0..3 (8B)
        __builtin_amdgcn_s_setprio(1);
        #pragma unroll
        for (int n = 0; n < 4; ++n) {
            const int d = 64 * dh + 16 * n + l16;
            const int c = 2 * sh + (quad >> 1);      // 16B chunk of the row
            const bf16x4 vb = *(const bf16x4*)(Vtl + (size_t)d * BK +
                                    ((c ^ (d & 3)) << 3) + ((quad & 1) << 2));
            o[n] = __builtin_amdgcn_mfma_f32_16x16x16bf16_1k(pa, vb, o[n], 0, 0, 0);
        }
        __builtin_amdgcn_s_setprio(0);
    }

    // ---- epilogue: combine sh-halves, normalize, store ----
    // lane lsum covers keys {16sh+4quad+r} for q=l16: reduce quads
    lsum += __shfl_xor(lsum, 16, 64);
    lsum += __shfl_xor(lsum, 32, 64);

    __syncthreads();                       // all tile-loop LDS/DMA traffic done
    float* Osc = (float*)&Ks[0][0];        // [2 dh][16 q][64 d] fp32 = 8 KB

    if (dh == 0 && lane < 16) Lsc[sh][l16] = lsum;
    if (sh == 0) {
        #pragma unroll
        for (int n = 0; n < 4; ++n)
            #pragma unroll
            for (int r = 0; r < 4; ++r)
                Osc[((size_t)dh * 16 + 4 * quad + r) * 64 + 16 * n + l16] = o[n][r];
    }
    __syncthreads();
    if (sh == 1) {
        #pragma unroll
        for (int r = 0; r < 4; ++r) {
            const int row = 4 * quad + r;
            const float ls = Lsc[0][row] + Lsc[1][row];
            const float inv = 1.0f / ls;
            #pragma unroll
            for (int n = 0; n < 4; ++n) {
                const float val = (o[n][r] +
                    Osc[((size_t)dh * 16 + row) * 64 + 16 * n + l16]) * inv;
                Out[((size_t)b * SEQ + q0 + row) * DH + 64 * dh + 16 * n + l16] = val;
            }
        }
    }
}

// ============================================================================
// Fallback (ws too small): self-contained fp32 kernel (round-1, known-good)
// ============================================================================
#define FBQ 32
#define FBK 64
#define QSTRIDE (DH + 4)
#define PSTRIDE (FBK + 4)
__global__ __launch_bounds__(NT, 2)
void attn_fwd(const float* __restrict__ Q, const float* __restrict__ K,
              const float* __restrict__ V, const int* __restrict__ vlens,
              float* __restrict__ Out) {
    __shared__ float Qs[FBQ][QSTRIDE];
    __shared__ float KVs[FBK][QSTRIDE];
    __shared__ float Ps[FBQ][PSTRIDE];
    __shared__ float l_s[FBQ];
    const int tid = threadIdx.x;
    const int b = blockIdx.y, q0 = blockIdx.x * FBQ;
    const int vl = vlens[b];
    const float scale = 0.088388347648318441f;
    const float* Qb = Q + ((size_t)b * SEQ + q0) * DH;
    const float* Kb = K + (size_t)b * SEQ * DH;
    const float* Vb = V + (size_t)b * SEQ * DH;
    {
        const int r = tid >> 5, c4 = (tid & 31) * 4;
        #pragma unroll
        for (int i = 0; i < 4; ++i)
            *(float4*)&Qs[i * 8 + r][c4] = *(const float4*)(Qb + (size_t)(i * 8 + r) * DH + c4);
    }
    const int sty = tid >> 4, stx = tid & 15;
    const int brow = tid >> 3, bpart = tid & 7;
    const int prg = tid >> 5, pcg = tid & 31;
    float lacc = 0.0f;
    float O[4][4];
    #pragma unroll
    for (int i = 0; i < 4; ++i)
        #pragma unroll
        for (int jj = 0; jj < 4; ++jj) O[i][jj] = 0.0f;
    const int ntiles = (vl + FBK - 1) / FBK;
    for (int t = 0; t < ntiles; ++t) {
        const int k0 = t * FBK;
        __syncthreads();
        {
            const int r = tid >> 5, c4 = (tid & 31) * 4;
            #pragma unroll
            for (int i = 0; i < 8; ++i)
                *(float4*)&KVs[i * 8 + r][c4] = *(const float4*)(Kb + (size_t)(k0 + i * 8 + r) * DH + c4);
        }
        __syncthreads();
        float s0[4] = {0.f, 0.f, 0.f, 0.f}, s1[4] = {0.f, 0.f, 0.f, 0.f};
        #pragma unroll 2
        for (int d = 0; d < DH; d += 4) {
            const float4 qa = *(const float4*)&Qs[2 * sty][d];
            const float4 qb = *(const float4*)&Qs[2 * sty + 1][d];
            #pragma unroll
            for (int jj = 0; jj < 4; ++jj) {
                const float4 kk = *(const float4*)&KVs[4 * stx + jj][d];
                s0[jj] += qa.x * kk.x + qa.y * kk.y + qa.z * kk.z + qa.w * kk.w;
                s1[jj] += qb.x * kk.x + qb.y * kk.y + qb.z * kk.z + qb.w * kk.w;
            }
        }
        #pragma unroll
        for (int jj = 0; jj < 4; ++jj) {
            const int kk = k0 + 4 * stx + jj;
            const bool valid = kk < vl;
            Ps[2 * sty][4 * stx + jj]     = valid ? __expf(s0[jj] * scale - CFIX) : 0.f;
            Ps[2 * sty + 1][4 * stx + jj] = valid ? __expf(s1[jj] * scale - CFIX) : 0.f;
        }
        __syncthreads();
        {
            float ps = 0.f;
            #pragma unroll
            for (int i = 0; i < 8; ++i) ps += Ps[brow][bpart * 8 + i];
            #pragma unroll
            for (int off = 1; off < 8; off <<= 1) ps += __shfl_xor(ps, off, 64);
            if (bpart == 0) lacc += ps;
        }
        {
            const int r = tid >> 5, c4 = (tid & 31) * 4;
            float4 vreg[8];
            #pragma unroll
            for (int i = 0; i < 8; ++i)
                vreg[i] = *(const float4*)(Vb + (size_t)(k0 + i * 8 + r) * DH + c4);
            __syncthreads();
            #pragma unroll
            for (int i = 0; i < 8; ++i) *(float4*)&KVs[i * 8 + r][c4] = vreg[i];
        }
        __syncthreads();
        for (int k = 0; k < FBK; k += 4) {
            float4 pr[4];
            #pragma unroll
            for (int i = 0; i < 4; ++i) pr[i] = *(const float4*)&Ps[prg * 4 + i][k];
            #pragma unroll
            for (int k2 = 0; k2 < 4; ++k2) {
                const float4 vv = *(const float4*)&KVs[k + k2][pcg * 4];
                #pragma unroll
                for (int i = 0; i < 4; ++i) {
                    const float p = ((const float*)&pr[i])[k2];
                    O[i][0] += p * vv.x; O[i][1] += p * vv.y;
                    O[i][2] += p * vv.z; O[i][3] += p * vv.w;
                }
            }
        }
    }
    if (bpart == 0) l_s[brow] = lacc;
    __syncthreads();
    float* Ob = Out + ((size_t)b * SEQ + q0) * DH;
    #pragma unroll
    for (int i = 0; i < 4; ++i) {
        const int row = prg * 4 + i;
        const float inv = 1.0f / l_s[row];
        float4 ov;
        ov.x = O[i][0] * inv; ov.y = O[i][1] * inv;
        ov.z = O[i][2] * inv; ov.w = O[i][3] * inv;
        *(float4*)(Ob + (size_t)row * DH + pcg * 4) = ov;
    }
}

extern "C" void kernel_launch(void* const* d_in, const int* in_sizes, int n_in,
                              void* d_out, int out_size, void* d_ws, size_t ws_size,
                              hipStream_t stream) {
    const float* Q = (const float*)d_in[0];
    const float* K = (const float*)d_in[1];
    const float* V = (const float*)d_in[2];
    const int* vlens = (const int*)d_in[3];
    float* Out = (float*)d_out;

    const size_t n = (size_t)BS * SEQ * DH;     // 2,097,152
    const size_t need = 3 * n * 2;              // Qbf + Kbf + Vt, 12 MiB

    if (ws_size >= need) {
        unsigned short* Kbf = (unsigned short*)d_ws;
        unsigned short* Vt  = Kbf + n;
        unsigned short* Qbf = Vt + n;
        conv_all<<<dim3(256), dim3(NT), 0, stream>>>(Q, K, V, Qbf, Kbf, Vt);
        attn16<<<dim3(BS * (SEQ / BQ)), dim3(NT), 0, stream>>>(Qbf, Kbf, Vt, vlens, Out);
    } else {
        attn_fwd<<<dim3(SEQ / FBQ, BS), dim3(NT), 0, stream>>>(Q, K, V, vlens, Out);
    }
}

// Round 8
// 110.293 us; speedup vs baseline: 1.1697x; 1.1697x over previous
//
#include <hip/hip_runtime.h>

typedef float f32x4 __attribute__((ext_vector_type(4)));
typedef short bf16x8 __attribute__((ext_vector_type(8)));
typedef short bf16x4 __attribute__((ext_vector_type(4)));
typedef unsigned int u32x2 __attribute__((ext_vector_type(2)));

#define BS    8
#define SEQ   2048
#define DH    128
#define BQ    64       /* q-rows per block: two 32-row q-groups */
#define BK    64
#define NT    256
#define CFIX  8.0f
#define SC2E  0.12751743f       /* (1/sqrt(128)) * log2(e) */
#define NC2E  -11.541560327f    /* -CFIX * log2(e)         */

__device__ __forceinline__ unsigned short f2bf(float x) {
    unsigned u = __float_as_uint(x);
    u += 0x7FFFu + ((u >> 16) & 1u);   // RNE
    return (unsigned short)(u >> 16);
}

// async 16B global->LDS (lds dest = wave-uniform base + lane*16)
__device__ __forceinline__ void gl_lds16(const unsigned short* g, unsigned short* l) {
    __builtin_amdgcn_global_load_lds(
        (const __attribute__((address_space(1))) unsigned int*)g,
        (__attribute__((address_space(3))) unsigned int*)l, 16, 0, 0);
}

// ============================================================================
// Kernel 1: K -> bf16 flat; V -> Vt[b][d][s] bf16. 256 blocks x 256 thr.
// (Champion version, verbatim.)
// ============================================================================
__global__ __launch_bounds__(NT)
void conv_all(const float* __restrict__ K, const float* __restrict__ V,
              unsigned short* __restrict__ Kbf, unsigned short* __restrict__ Vt) {
    __shared__ unsigned short T[64][132];
    const int tid = threadIdx.x;
    const int bid = blockIdx.x;

    const int gtid = bid * NT + tid;
    #pragma unroll
    for (int i = 0; i < 8; ++i) {
        const int idx = i * (256 * NT) + gtid;
        float4 v = ((const float4*)K)[idx];
        ushort4 h;
        h.x = f2bf(v.x); h.y = f2bf(v.y); h.z = f2bf(v.z); h.w = f2bf(v.w);
        ((ushort4*)Kbf)[idx] = h;
    }

    const int vb = bid >> 5, s0 = (bid & 31) * 64;
    const float* Vb = V + ((size_t)vb * SEQ + s0) * DH;
    #pragma unroll
    for (int i = 0; i < 8; ++i) {
        const int row = i * 8 + (tid >> 5);
        const int col = (tid & 31) * 4;
        float4 v = *(const float4*)(Vb + (size_t)row * DH + col);
        ushort4 h;
        h.x = f2bf(v.x); h.y = f2bf(v.y); h.z = f2bf(v.z); h.w = f2bf(v.w);
        *(ushort4*)&T[row][col] = h;
    }
    __syncthreads();
    const int d = tid >> 1, sh = (tid & 1) * 32;
    unsigned short tmp[32] __attribute__((aligned(16)));
    #pragma unroll
    for (int s = 0; s < 32; ++s) tmp[s] = T[sh + s][d];
    unsigned short* dst = Vt + ((size_t)vb * DH + d) * SEQ + s0 + sh;
    #pragma unroll
    for (int g = 0; g < 4; ++g)
        *(uint4*)(dst + g * 8) = *(const uint4*)(tmp + g * 8);
}

// ============================================================================
// Kernel 2: flash attention, split-K 2-way + q-DOUBLED blocks (BQ=64).
// Grid = 512: bid -> (h = key-half, b, 64-row q-chunk). Each staged 32 KB
// K/V tile now serves 64 q-rows (two register-resident 32-row q-groups) --
// HALF the total L2/L3 staging traffic of the 32-q version. Tile body,
// staging, swizzles = R3's validated code; q-group dimension = R2's
// validated register fattening (qf[2][4], o[2][8], s2[2][2]).
// Wave (qh=wid>>1, sh=wid&1): per q-group, 16 q-rows x 32-key half.
// Outputs UNNORMALIZED partial O + per-row lsum; combine kernel finishes.
// ============================================================================
__global__ __launch_bounds__(NT, 2)
void attn64sk(const float* __restrict__ Q, const unsigned short* __restrict__ Kbf,
              const unsigned short* __restrict__ Vt, const int* __restrict__ vlens,
              float* __restrict__ Oh, float* __restrict__ Lh) {
    __shared__ unsigned short Ks[2][BK * DH];     // 32 KB (also epilogue O scratch)
    __shared__ unsigned short Vs[2][DH * BK];     // 32 KB
    __shared__ float Lsc[2][64];                  // per-half row sums (512 B)

    const int tid  = threadIdx.x;
    const int wid  = tid >> 6, lane = tid & 63;
    const int quad = lane >> 4, l16 = lane & 15;
    const int qh   = wid >> 1, sh = wid & 1;
    const int bid  = blockIdx.x;
    const int h    = bid & 1;                  // key-half
    const int rest = bid >> 1;
    const int b    = rest >> 5;
    const int q0   = (rest & 31) * BQ;
    const int vl   = vlens[b];

    const int ntAll = (vl + BK - 1) >> 6;
    const int t0 = h << 4;                     // 16 tiles per half
    const int t1 = min(ntAll, (h + 1) << 4);

    float* Lrow = Lh + ((size_t)h * BS + b) * SEQ + q0;
    if (t0 >= t1) {                            // this half has no keys
        if (tid < BQ) Lrow[tid] = 0.0f;
        return;
    }

    const unsigned short* Kb  = Kbf + (size_t)b * SEQ * DH;
    const unsigned short* Vtb = Vt  + (size_t)b * DH * SEQ;

    // Q fragments for both q-groups (q = q0 + 32*qg + 16*qh + l16).
    // B-frag lane layout == A-frag layout -> same regs serve swapped QK^T.
    bf16x8 qf[2][4];
    #pragma unroll
    for (int qg = 0; qg < 2; ++qg) {
        const float* Qr = Q + ((size_t)b * SEQ + q0 + 32 * qg + 16 * qh + l16) * DH;
        #pragma unroll
        for (int ks = 0; ks < 4; ++ks) {
            const float4 x = *(const float4*)(Qr + 32 * ks + 8 * quad);
            const float4 y = *(const float4*)(Qr + 32 * ks + 8 * quad + 4);
            unsigned short t8[8] __attribute__((aligned(16)));
            t8[0] = f2bf(x.x); t8[1] = f2bf(x.y); t8[2] = f2bf(x.z); t8[3] = f2bf(x.w);
            t8[4] = f2bf(y.x); t8[5] = f2bf(y.y); t8[6] = f2bf(y.z); t8[7] = f2bf(y.w);
            qf[qg][ks] = *(const bf16x8*)t8;
        }
    }

    f32x4 o[2][8];
    #pragma unroll
    for (int qg = 0; qg < 2; ++qg)
        #pragma unroll
        for (int n = 0; n < 8; ++n) o[qg][n] = (f32x4){0.f, 0.f, 0.f, 0.f};
    float lsum[2] = {0.f, 0.f};

    // wave w stages K rows 16w..+15 and V d-rows 32w..+31 (16B XOR-swizzled)
    auto stage = [&](int buf, int k0) {
        unsigned short* KsB = &Ks[buf][0];
        unsigned short* VsB = &Vs[buf][0];
        #pragma unroll
        for (int ii = 0; ii < 4; ++ii) {
            const int rb = 16 * wid + 4 * ii;
            const int r  = rb + (lane >> 4);
            const int c  = lane & 15;
            gl_lds16(Kb + (size_t)(k0 + r) * DH + ((c ^ (r & 15)) << 3),
                     KsB + (size_t)rb * DH);
        }
        #pragma unroll
        for (int jj = 0; jj < 4; ++jj) {
            const int db = 32 * wid + 8 * jj;
            const int d  = db + (lane >> 3);
            const int c  = lane & 7;
            gl_lds16(Vtb + (size_t)d * SEQ + k0 + ((c ^ (d & 7)) << 3),
                     VsB + (size_t)db * BK);
        }
    };

    stage(0, t0 << 6);

    for (int t = t0; t < t1; ++t) {
        const int k0 = t << 6;
        __syncthreads();      // vmcnt drained: buf[t&1] staged; prev reads done
        if (t + 1 < t1) stage((t + 1) & 1, k0 + BK);

        const unsigned short* Kt  = &Ks[t & 1][0];
        const unsigned short* Vtl = &Vs[t & 1][0];

        // ---- S^T = K Q^T (swapped): lane -> q=l16, keys 16*nt+4*quad+r ----
        // One K-fragment read feeds BOTH q-groups' MFMAs.
        f32x4 s2[2][2];
        #pragma unroll
        for (int qg = 0; qg < 2; ++qg) {
            s2[qg][0] = (f32x4){0.f, 0.f, 0.f, 0.f};
            s2[qg][1] = (f32x4){0.f, 0.f, 0.f, 0.f};
        }
        __builtin_amdgcn_s_setprio(1);
        #pragma unroll
        for (int ks = 0; ks < 4; ++ks) {
            bf16x8 bk[2];
            #pragma unroll
            for (int nt = 0; nt < 2; ++nt)
                bk[nt] = *(const bf16x8*)(Kt + (size_t)(32 * sh + 16 * nt + l16) * DH +
                                          (((4 * ks + quad) ^ l16) << 3));
            #pragma unroll
            for (int nt = 0; nt < 2; ++nt)
                #pragma unroll
                for (int qg = 0; qg < 2; ++qg)
                    s2[qg][nt] = __builtin_amdgcn_mfma_f32_16x16x32_bf16(
                        bk[nt], qf[qg][ks], s2[qg][nt], 0, 0, 0);
        }
        __builtin_amdgcn_s_setprio(0);

        // ---- fixed-C softmax, fully in-register, both q-groups ----
        float p[2][2][4];
        if (k0 + BK <= vl) {               // full tile: no masking at all
            #pragma unroll
            for (int qg = 0; qg < 2; ++qg)
                #pragma unroll
                for (int nt = 0; nt < 2; ++nt)
                    #pragma unroll
                    for (int r = 0; r < 4; ++r) {
                        const float pv = __builtin_amdgcn_exp2f(fmaf(s2[qg][nt][r], SC2E, NC2E));
                        p[qg][nt][r] = pv;
                        lsum[qg] += pv;
                    }
        } else {                           // last (partial) tile only
            const int kb = k0 + 32 * sh + 4 * quad;
            #pragma unroll
            for (int qg = 0; qg < 2; ++qg)
                #pragma unroll
                for (int nt = 0; nt < 2; ++nt)
                    #pragma unroll
                    for (int r = 0; r < 4; ++r) {
                        float pv = __builtin_amdgcn_exp2f(fmaf(s2[qg][nt][r], SC2E, NC2E));
                        pv = (kb + 16 * nt + r < vl) ? pv : 0.0f;
                        p[qg][nt][r] = pv;
                        lsum[qg] += pv;
                    }
        }

        // ---- pack P -> bf16 K=16 A-fragments: pa[qg][nt] ----
        bf16x4 pa[2][2];
        #pragma unroll
        for (int qg = 0; qg < 2; ++qg)
            #pragma unroll
            for (int nt = 0; nt < 2; ++nt) {
                unsigned w0, w1;
                asm("v_cvt_pk_bf16_f32 %0, %1, %2" : "=v"(w0) : "v"(p[qg][nt][0]), "v"(p[qg][nt][1]));
                asm("v_cvt_pk_bf16_f32 %0, %1, %2" : "=v"(w1) : "v"(p[qg][nt][2]), "v"(p[qg][nt][3]));
                u32x2 tw; tw.x = w0; tw.y = w1;
                pa[qg][nt] = __builtin_bit_cast(bf16x4, tw);
            }

        // ---- partial O += P_half V_half: one V read feeds both q-groups ----
        __builtin_amdgcn_s_setprio(1);
        #pragma unroll
        for (int n = 0; n < 8; ++n) {
            const int dd = 16 * n + l16;
            #pragma unroll
            for (int nt = 0; nt < 2; ++nt) {
                const int g = 4 * sh + 2 * nt + (quad >> 1);   // 8-short V chunk
                const bf16x4 vb = *(const bf16x4*)(Vtl + (size_t)dd * BK +
                                        ((g ^ (dd & 7)) << 3) + ((quad & 1) << 2));
                #pragma unroll
                for (int qg = 0; qg < 2; ++qg)
                    o[qg][n] = __builtin_amdgcn_mfma_f32_16x16x16bf16_1k(
                        pa[qg][nt], vb, o[qg][n], 0, 0, 0);
            }
        }
        __builtin_amdgcn_s_setprio(0);
    }

    // ---- epilogue: combine the two s-halves, write UNNORMALIZED partial ----
    #pragma unroll
    for (int qg = 0; qg < 2; ++qg) {
        lsum[qg] += __shfl_xor(lsum[qg], 16, 64);
        lsum[qg] += __shfl_xor(lsum[qg], 32, 64);
    }

    __syncthreads();                       // all tile-loop LDS/DMA traffic done
    float* Osc = (float*)&Ks[0][0];        // 2qg x 2qh x 16 x 128 fp32 = 32 KB

    if (lane < 16) {
        Lsc[sh][qh * 16 + l16]      = lsum[0];
        Lsc[sh][32 + qh * 16 + l16] = lsum[1];
    }
    if (sh == 0) {
        #pragma unroll
        for (int qg = 0; qg < 2; ++qg)
            #pragma unroll
            for (int r = 0; r < 4; ++r) {
                float* dst = Osc + (size_t)qg * 4096 + (size_t)qh * 2048 +
                             (4 * quad + r) * 128 + l16;
                #pragma unroll
                for (int n = 0; n < 8; ++n) dst[16 * n] = o[qg][n][r];
            }
    }
    __syncthreads();
    if (sh == 1) {
        #pragma unroll
        for (int qg = 0; qg < 2; ++qg)
            #pragma unroll
            for (int r = 0; r < 4; ++r) {
                const int rloc = qh * 16 + 4 * quad + r;
                const int row  = 32 * qg + rloc;
                const float ls = Lsc[0][32 * qg + rloc] + Lsc[1][32 * qg + rloc];
                const float* src = Osc + (size_t)qg * 4096 + (size_t)qh * 2048 +
                                   (4 * quad + r) * 128 + l16;
                float* Or = Oh + (((size_t)h * BS + b) * SEQ + q0 + row) * DH + l16;
                #pragma unroll
                for (int n = 0; n < 8; ++n)
                    Or[16 * n] = o[qg][n][r] + src[16 * n];
                if (l16 == 0) Lrow[row] = ls;
            }
    }
}

// ============================================================================
// Kernel 3: combine split-K halves: Out = (O0 + O1) / (l0 + l1).
// Grid 512 x 256 thr; each thread finalizes 16 floats. Empty halves wrote
// l1 = 0 (and no O1) -> branch skips the poison read. (R3 version, verbatim.)
// ============================================================================
__global__ __launch_bounds__(NT)
void combine(const float* __restrict__ Oh, const float* __restrict__ Lh,
             float* __restrict__ Out) {
    const int bid = blockIdx.x;
    const int tid = threadIdx.x;
    const int b = bid >> 6, q0 = (bid & 63) * 32;
    const int row = q0 + (tid >> 3);
    const int c0 = (tid & 7) * 16;
    const size_t r0 = (size_t)b * SEQ + row;

    const float l0 = Lh[r0];
    const float l1 = Lh[(size_t)BS * SEQ + r0];
    const float inv = 1.0f / (l0 + l1);

    const float* p0 = Oh + r0 * DH + c0;
    const float* p1 = Oh + (size_t)BS * SEQ * DH + r0 * DH + c0;
    float* po = Out + r0 * DH + c0;

    if (l1 != 0.0f) {
        #pragma unroll
        for (int j = 0; j < 4; ++j) {
            f32x4 a = *(const f32x4*)(p0 + 4 * j) + *(const f32x4*)(p1 + 4 * j);
            float4 ov;
            ov.x = a[0] * inv; ov.y = a[1] * inv;
            ov.z = a[2] * inv; ov.w = a[3] * inv;
            *(float4*)(po + 4 * j) = ov;
        }
    } else {
        #pragma unroll
        for (int j = 0; j < 4; ++j) {
            const f32x4 a = *(const f32x4*)(p0 + 4 * j);
            float4 ov;
            ov.x = a[0] * inv; ov.y = a[1] * inv;
            ov.z = a[2] * inv; ov.w = a[3] * inv;
            *(float4*)(po + 4 * j) = ov;
        }
    }
}

// ============================================================================
// Fallback (ws too small): self-contained fp32 kernel (round-1, known-good)
// ============================================================================
#define FBQ 32
#define FBK 64
#define QSTRIDE (DH + 4)
#define PSTRIDE (FBK + 4)
__global__ __launch_bounds__(NT, 2)
void attn_fwd(const float* __restrict__ Q, const float* __restrict__ K,
              const float* __restrict__ V, const int* __restrict__ vlens,
              float* __restrict__ Out) {
    __shared__ float Qs[FBQ][QSTRIDE];
    __shared__ float KVs[FBK][QSTRIDE];
    __shared__ float Ps[FBQ][PSTRIDE];
    __shared__ float l_s[FBQ];
    const int tid = threadIdx.x;
    const int b = blockIdx.y, q0 = blockIdx.x * FBQ;
    const int vl = vlens[b];
    const float scale = 0.088388347648318441f;
    const float* Qb = Q + ((size_t)b * SEQ + q0) * DH;
    const float* Kb = K + (size_t)b * SEQ * DH;
    const float* Vb = V + (size_t)b * SEQ * DH;
    {
        const int r = tid >> 5, c4 = (tid & 31) * 4;
        #pragma unroll
        for (int i = 0; i < 4; ++i)
            *(float4*)&Qs[i * 8 + r][c4] = *(const float4*)(Qb + (size_t)(i * 8 + r) * DH + c4);
    }
    const int sty = tid >> 4, stx = tid & 15;
    const int brow = tid >> 3, bpart = tid & 7;
    const int prg = tid >> 5, pcg = tid & 31;
    float lacc = 0.0f;
    float O[4][4];
    #pragma unroll
    for (int i = 0; i < 4; ++i)
        #pragma unroll
        for (int jj = 0; jj < 4; ++jj) O[i][jj] = 0.0f;
    const int ntiles = (vl + FBK - 1) / FBK;
    for (int t = 0; t < ntiles; ++t) {
        const int k0 = t * FBK;
        __syncthreads();
        {
            const int r = tid >> 5, c4 = (tid & 31) * 4;
            #pragma unroll
            for (int i = 0; i < 8; ++i)
                *(float4*)&KVs[i * 8 + r][c4] = *(const float4*)(Kb + (size_t)(k0 + i * 8 + r) * DH + c4);
        }
        __syncthreads();
        float s0[4] = {0.f, 0.f, 0.f, 0.f}, s1[4] = {0.f, 0.f, 0.f, 0.f};
        #pragma unroll 2
        for (int d = 0; d < DH; d += 4) {
            const float4 qa = *(const float4*)&Qs[2 * sty][d];
            const float4 qb = *(const float4*)&Qs[2 * sty + 1][d];
            #pragma unroll
            for (int jj = 0; jj < 4; ++jj) {
                const float4 kk = *(const float4*)&KVs[4 * stx + jj][d];
                s0[jj] += qa.x * kk.x + qa.y * kk.y + qa.z * kk.z + qa.w * kk.w;
                s1[jj] += qb.x * kk.x + qb.y * kk.y + qb.z * kk.z + qb.w * kk.w;
            }
        }
        #pragma unroll
        for (int jj = 0; jj < 4; ++jj) {
            const int kk = k0 + 4 * stx + jj;
            const bool valid = kk < vl;
            Ps[2 * sty][4 * stx + jj]     = valid ? __expf(s0[jj] * scale - CFIX) : 0.f;
            Ps[2 * sty + 1][4 * stx + jj] = valid ? __expf(s1[jj] * scale - CFIX) : 0.f;
        }
        __syncthreads();
        {
            float ps = 0.f;
            #pragma unroll
            for (int i = 0; i < 8; ++i) ps += Ps[brow][bpart * 8 + i];
            #pragma unroll
            for (int off = 1; off < 8; off <<= 1) ps += __shfl_xor(ps, off, 64);
            if (bpart == 0) lacc += ps;
        }
        {
            const int r = tid >> 5, c4 = (tid & 31) * 4;
            float4 vreg[8];
            #pragma unroll
            for (int i = 0; i < 8; ++i)
                vreg[i] = *(const float4*)(Vb + (size_t)(k0 + i * 8 + r) * DH + c4);
            __syncthreads();
            #pragma unroll
            for (int i = 0; i < 8; ++i) *(float4*)&KVs[i * 8 + r][c4] = vreg[i];
        }
        __syncthreads();
        for (int k = 0; k < FBK; k += 4) {
            float4 pr[4];
            #pragma unroll
            for (int i = 0; i < 4; ++i) pr[i] = *(const float4*)&Ps[prg * 4 + i][k];
            #pragma unroll
            for (int k2 = 0; k2 < 4; ++k2) {
                const float4 vv = *(const float4*)&KVs[k + k2][pcg * 4];
                #pragma unroll
                for (int i = 0; i < 4; ++i) {
                    const float p = ((const float*)&pr[i])[k2];
                    O[i][0] += p * vv.x; O[i][1] += p * vv.y;
                    O[i][2] += p * vv.z; O[i][3] += p * vv.w;
                }
            }
        }
    }
    if (bpart == 0) l_s[brow] = lacc;
    __syncthreads();
    float* Ob = Out + ((size_t)b * SEQ + q0) * DH;
    #pragma unroll
    for (int i = 0; i < 4; ++i) {
        const int row = prg * 4 + i;
        const float inv = 1.0f / l_s[row];
        float4 ov;
        ov.x = O[i][0] * inv; ov.y = O[i][1] * inv;
        ov.z = O[i][2] * inv; ov.w = O[i][3] * inv;
        *(float4*)(Ob + (size_t)row * DH + pcg * 4) = ov;
    }
}

extern "C" void kernel_launch(void* const* d_in, const int* in_sizes, int n_in,
                              void* d_out, int out_size, void* d_ws, size_t ws_size,
                              hipStream_t stream) {
    const float* Q = (const float*)d_in[0];
    const float* K = (const float*)d_in[1];
    const float* V = (const float*)d_in[2];
    const int* vlens = (const int*)d_in[3];
    float* Out = (float*)d_out;

    const size_t n = (size_t)BS * SEQ * DH;            // 2,097,152
    const size_t need = 2 * n * 2                       // Kbf + Vt (8 MiB)
                      + 2 * n * 4                       // Oh partials (16 MiB)
                      + 2 * (size_t)BS * SEQ * 4;       // Lh partials (128 KiB)

    if (ws_size >= need) {
        unsigned short* Kbf = (unsigned short*)d_ws;
        unsigned short* Vt  = Kbf + n;
        float* Oh = (float*)(Vt + n);
        float* Lh = Oh + 2 * n;
        conv_all<<<dim3(256), dim3(NT), 0, stream>>>(K, V, Kbf, Vt);
        attn64sk<<<dim3(2 * BS * (SEQ / BQ)), dim3(NT), 0, stream>>>(Q, Kbf, Vt, vlens, Oh, Lh);
        combine<<<dim3(BS * (SEQ / 32)), dim3(NT), 0, stream>>>(Oh, Lh, Out);
    } else {
        attn_fwd<<<dim3(SEQ / FBQ, BS), dim3(NT), 0, stream>>>(Q, K, V, vlens, Out);
    }
}